// Round 1
// baseline (8771.647 us; speedup 1.0000x reference)
//
#include <hip/hip_runtime.h>
#include <hip/hip_bf16.h>

// GatedLSTM: B=64, T=256, IN=512, H=1024. i-gate computed-but-unused in the
// reference -> skipped in x-projection and elementwise (kept only as MFMA tile
// padding in the recurrent GEMM).

typedef __attribute__((ext_vector_type(8))) short bfrag;   // 8 x bf16 (4 VGPR)
typedef __attribute__((ext_vector_type(4))) float f32x4;   // MFMA accumulator

__device__ __forceinline__ unsigned short f2b(float v) {
  __hip_bfloat16 h = __float2bfloat16(v);
  union { __hip_bfloat16 h; unsigned short u; } c; c.h = h; return c.u;
}
__device__ __forceinline__ float b2f(unsigned short u) {
  union { unsigned int i; float f; } c; c.i = ((unsigned int)u) << 16; return c.f;
}
__device__ __forceinline__ float sigm(float x) { return 1.0f / (1.0f + __expf(-x)); }
__device__ __forceinline__ float tanh_f(float x) {
  float e = __expf(2.0f * x);
  return (e - 1.0f) / (e + 1.0f);
}

// ---------------------------------------------------------------------------
// Phase 1: x-projections. C = X[16384,512] @ {W,Wm}^T, fused ml = sig(xWm)*xW.
// Block tile: M=256 (4 t x 64 b), N=256 ({W,Wm} x 128 j), K=512 in 4 chunks.
// 8 waves; wave = 32 rows x all 256 cols -> holds xw AND xwm for same (b,j),
// combine in-register, store bf16 mlx[t][g][j][b].
// ---------------------------------------------------------------------------
__global__ __launch_bounds__(512, 2) void xproj_kernel(
    const float* __restrict__ inp,
    const float* __restrict__ Wf, const float* __restrict__ Wmf,
    const float* __restrict__ Wo, const float* __restrict__ Wmo,
    const float* __restrict__ Wc, const float* __restrict__ Wmc,
    unsigned short* __restrict__ mlx)
{
  __shared__ unsigned short Al[256 * 128];  // 64 KB, XOR-swizzled rows
  __shared__ unsigned short Bl[256 * 128];  // 64 KB

  const int tid = threadIdx.x;
  const int w = tid >> 6, l = tid & 63;
  const int c = l & 15, g4 = l >> 4;
  const int jc = blockIdx.x, gate = blockIdx.y, tq = blockIdx.z;
  const float* W  = (gate == 0) ? Wf  : (gate == 1) ? Wo  : Wc;
  const float* Wm = (gate == 0) ? Wmf : (gate == 1) ? Wmo : Wmc;
  const int j0 = jc * 128;

  f32x4 acc[2][16];
#pragma unroll
  for (int mi = 0; mi < 2; ++mi)
#pragma unroll
    for (int ni = 0; ni < 16; ++ni) acc[mi][ni] = (f32x4){0.f, 0.f, 0.f, 0.f};

  for (int kc = 0; kc < 4; ++kc) {
#pragma unroll
    for (int i = 0; i < 16; ++i) {
      int idx = tid + i * 512;      // 0..8191
      int row = idx >> 5;           // 0..255
      int xl  = idx & 31;           // 16B unit within 128-float chunk
      // A: row = tloc*64 + b  -> input[b][tq*4+tloc][k]
      int b_ = row & 63, tl = row >> 6;
      const float4 va = *(const float4*)(inp + (size_t)(b_ * 256 + tq * 4 + tl) * 512 + kc * 128 + xl * 4);
      ushort4 pa;
      pa.x = f2b(va.x); pa.y = f2b(va.y); pa.z = f2b(va.z); pa.w = f2b(va.w);
      *(ushort4*)((char*)Al + ((row * 256 + xl * 8) ^ ((row & 7) << 4))) = pa;
      // B: rows 0..127 = W[j0+row], 128..255 = Wm[j0+row-128]
      const float* src = (row < 128) ? (W + (size_t)(j0 + row) * 512)
                                     : (Wm + (size_t)(j0 + row - 128) * 512);
      const float4 vb = *(const float4*)(src + kc * 128 + xl * 4);
      ushort4 pb;
      pb.x = f2b(vb.x); pb.y = f2b(vb.y); pb.z = f2b(vb.z); pb.w = f2b(vb.w);
      *(ushort4*)((char*)Bl + ((row * 256 + xl * 8) ^ ((row & 7) << 4))) = pb;
    }
    __syncthreads();
#pragma unroll
    for (int ks = 0; ks < 4; ++ks) {
      const int koff = (ks * 32 + g4 * 8) * 2;   // byte offset within row
      bfrag af[2];
#pragma unroll
      for (int mi = 0; mi < 2; ++mi) {
        int row = w * 32 + mi * 16 + c;
        af[mi] = *(const bfrag*)((const char*)Al + ((row * 256 + koff) ^ ((row & 7) << 4)));
      }
#pragma unroll
      for (int ni = 0; ni < 16; ++ni) {
        int n = ni * 16 + c;
        bfrag bf = *(const bfrag*)((const char*)Bl + ((n * 256 + koff) ^ ((n & 7) << 4)));
#pragma unroll
        for (int mi = 0; mi < 2; ++mi)
          acc[mi][ni] = __builtin_amdgcn_mfma_f32_16x16x32_bf16(af[mi], bf, acc[mi][ni], 0, 0, 0);
      }
    }
    __syncthreads();
  }
  // epilogue: ml = xw * sigmoid(xwm); lane's 4 regs = 4 consecutive b
#pragma unroll
  for (int mi = 0; mi < 2; ++mi) {
#pragma unroll
    for (int ni = 0; ni < 8; ++ni) {
      f32x4 xw = acc[mi][ni];
      f32x4 xm = acc[mi][ni + 8];
      ushort4 st;
      st.x = f2b(xw[0] * sigm(xm[0]));
      st.y = f2b(xw[1] * sigm(xm[1]));
      st.z = f2b(xw[2] * sigm(xm[2]));
      st.w = f2b(xw[3] * sigm(xm[3]));
      int row = w * 32 + mi * 16 + g4 * 4;   // +r handled by ushort4 (b+0..3)
      int tl = row >> 6, b_ = row & 63;
      int j = j0 + ni * 16 + c;
      size_t addr = ((size_t)((tq * 4 + tl) * 3 + gate) * 1024 + j) * 64 + b_;
      *(ushort4*)(mlx + addr) = st;
    }
  }
}

// ---------------------------------------------------------------------------
// Phase 2: persistent recurrent kernel. 256 blocks x 256 threads, 1 block/CU
// (LDS ~101KB forces it) -> all blocks co-resident; grid sync via agent-scope
// atomic counters (release add / relaxed spin / acquire fence).
// Block bid owns h-cols j0=4*bid..+4. B (32 U-rows x K=1024) lives in LDS the
// whole kernel. Per step: waves split K (256 each), MFMA 64x32, partial-sum
// reduce via LDS, elementwise gate math (c in a VGPR), h broadcast to 8
// per-XCD copies in global.
// ---------------------------------------------------------------------------
__global__ __launch_bounds__(256, 1) void recur_kernel(
    const float* __restrict__ Uf, const float* __restrict__ Umf,
    const float* __restrict__ Uo, const float* __restrict__ Umo,
    const float* __restrict__ Uc, const float* __restrict__ Umc,
    const float* __restrict__ Ui, const float* __restrict__ Umi,
    const float* __restrict__ bfp, const float* __restrict__ bop,
    const float* __restrict__ bcp,
    const unsigned short* __restrict__ mlx,  // [256][3][1024][64] bf16
    unsigned short* __restrict__ hbuf,       // [2][8][64][1024] bf16
    float* __restrict__ hhist,               // [256][1024][64] f32
    float* __restrict__ cfin,                // [1024][64] f32
    unsigned int* __restrict__ ctr)          // [256]
{
  __shared__ unsigned short Blds[32 * 1024];   // 64 KB, XOR-swizzled
  __shared__ float prep[4 * 32 * 68];          // 34.8 KB partials [w][col][row]
  __shared__ unsigned short hlds[64 * 4];      // h bf16 [b][jj]

  const int tid = threadIdx.x;
  const int bid = blockIdx.x;
  const int w = tid >> 6, l = tid & 63;
  const int c = l & 15, g4 = l >> 4;
  const int j0 = bid * 4;

  // one-time B stage: n = m*4+jj; mats {Uf,Umf,Uo,Umo,Uc,Umc,Ui,Umi} (i = pad)
  {
    const float* mats[8] = {Uf, Umf, Uo, Umo, Uc, Umc, Ui, Umi};
    int n = tid >> 3, sub = tid & 7;
    const float* src = mats[n >> 2] + (size_t)(j0 + (n & 3)) * 1024;
#pragma unroll
    for (int i = 0; i < 32; ++i) {
      int k = sub * 128 + i * 4;
      float4 v = *(const float4*)(src + k);
      ushort4 p;
      p.x = f2b(v.x); p.y = f2b(v.y); p.z = f2b(v.z); p.w = f2b(v.w);
      *(ushort4*)((char*)Blds + (((n * 1024 + k) * 2) ^ ((n & 7) << 4))) = p;
    }
  }
  const int jj = tid >> 6, bb = tid & 63;
  const float biasf = bfp[j0 + jj], biaso = bop[j0 + jj], biasc = bcp[j0 + jj];
  float creg = 0.0f;
  const int copy = bid & 7;   // XCD-local h copy
  __syncthreads();

  for (int t = 0; t < 256; ++t) {
    const unsigned short* hr = hbuf + ((size_t)(t & 1) * 8 + copy) * 65536;
    // prefetch this step's mlx (independent of h -> overlaps MFMA)
    const size_t mbase = (size_t)t * 3 * 65536 + (size_t)(j0 + jj) * 64 + bb;
    float mf = b2f(mlx[mbase]);
    float mo = b2f(mlx[mbase + 65536]);
    float mc = b2f(mlx[mbase + 2 * 65536]);

    f32x4 acc[4][2];
#pragma unroll
    for (int mi = 0; mi < 4; ++mi)
#pragma unroll
      for (int nt = 0; nt < 2; ++nt) acc[mi][nt] = (f32x4){0.f, 0.f, 0.f, 0.f};

#pragma unroll
    for (int ks = 0; ks < 8; ++ks) {
      const int k = w * 256 + ks * 32 + g4 * 8;   // wave-private K slice
      bfrag bfr[2];
#pragma unroll
      for (int nt = 0; nt < 2; ++nt) {
        int n = nt * 16 + c;
        bfr[nt] = *(const bfrag*)((const char*)Blds + (((n * 1024 + k) * 2) ^ ((n & 7) << 4)));
      }
#pragma unroll
      for (int mi = 0; mi < 4; ++mi) {
        const bfrag af = *(const bfrag*)(hr + (size_t)(mi * 16 + c) * 1024 + k);
#pragma unroll
        for (int nt = 0; nt < 2; ++nt)
          acc[mi][nt] = __builtin_amdgcn_mfma_f32_16x16x32_bf16(af, bfr[nt], acc[mi][nt], 0, 0, 0);
      }
    }
    // partials -> LDS [w][col][row] (col-major so 4 regs = b128)
#pragma unroll
    for (int mi = 0; mi < 4; ++mi)
#pragma unroll
      for (int nt = 0; nt < 2; ++nt) {
        int col = nt * 16 + c;
        *(f32x4*)&prep[(w * 32 + col) * 68 + mi * 16 + g4 * 4] = acc[mi][nt];
      }
    __syncthreads();

    // elementwise: thread (jj, bb); cols n = m*4+jj, m in {0..5}
#define RDP(m) (prep[((m) * 4 + jj) * 68 + bb] + prep[(32 + (m) * 4 + jj) * 68 + bb] + \
                prep[(64 + (m) * 4 + jj) * 68 + bb] + prep[(96 + (m) * 4 + jj) * 68 + bb])
    float s0 = RDP(0), s1 = RDP(1), s2 = RDP(2), s3 = RDP(3), s4 = RDP(4), s5 = RDP(5);
#undef RDP
    float fg = sigm(mf + sigm(s1) * s0 + biasf);
    float og = sigm(mo + sigm(s3) * s2 + biaso);
    float cd = tanh_f(mc + sigm(s5) * s4 + biasc);
    creg = fg * creg + cd;
    float hv = og * creg;
    hhist[(size_t)((t * 1024) + j0 + jj) * 64 + bb] = hv;
    hlds[bb * 4 + jj] = f2b(hv);
    if (t == 255) cfin[(size_t)(j0 + jj) * 64 + bb] = creg;
    __syncthreads();

    // wave0 broadcasts this block's 4 h-cols to the 8 per-XCD copies
    if (tid < 64) {
      ushort4 hv4 = *(ushort4*)&hlds[tid * 4];
      unsigned short* wb = hbuf + (size_t)((t + 1) & 1) * 8 * 65536 + (size_t)tid * 1024 + j0;
#pragma unroll
      for (int cp = 0; cp < 8; ++cp)
        *(ushort4*)(wb + (size_t)cp * 65536) = hv4;
    }
    __syncthreads();   // drains vmcnt -> stores in L2 before release

    if (tid == 0) {
      __hip_atomic_fetch_add(&ctr[t], 1u, __ATOMIC_RELEASE, __HIP_MEMORY_SCOPE_AGENT);
      while (__hip_atomic_load(&ctr[t], __ATOMIC_RELAXED, __HIP_MEMORY_SCOPE_AGENT) < 256u)
        __builtin_amdgcn_s_sleep(1);
    }
    __syncthreads();
    __builtin_amdgcn_fence(__ATOMIC_ACQUIRE, "agent");  // invalidate stale L1/L2
  }
}

// ---------------------------------------------------------------------------
// Phase 3: hhist [t][j][b] -> out [b][t][j]  (coalesced both sides via LDS)
// ---------------------------------------------------------------------------
__global__ __launch_bounds__(256) void transpose_kernel(
    const float* __restrict__ hhist, float* __restrict__ out)
{
  __shared__ float tile[64][65];
  const int tid = threadIdx.x;
  const int t = blockIdx.x, jc = blockIdx.y;
#pragma unroll
  for (int i = 0; i < 16; ++i) {
    int j = i * 4 + (tid >> 6);
    tile[j][tid & 63] = hhist[(size_t)(t * 1024 + jc * 64 + j) * 64 + (tid & 63)];
  }
  __syncthreads();
#pragma unroll
  for (int i = 0; i < 16; ++i) {
    int b = i * 4 + (tid >> 6);
    int j = tid & 63;
    out[((size_t)b * 256 + t) * 1024 + jc * 64 + j] = tile[j][b];
  }
}

__global__ __launch_bounds__(256) void finals_kernel(
    const float* __restrict__ hhist, const float* __restrict__ cfin,
    float* __restrict__ out)
{
  int tid = blockIdx.x * 256 + threadIdx.x;  // 0..65535 = b*1024 + j
  int b = tid >> 10, j = tid & 1023;
  out[16777216 + tid]         = hhist[(size_t)(255 * 1024 + j) * 64 + b];  // hT
  out[16777216 + 65536 + tid] = cfin[(size_t)j * 64 + b];                  // cT
}

// ---------------------------------------------------------------------------
extern "C" void kernel_launch(void* const* d_in, const int* in_sizes, int n_in,
                              void* d_out, int out_size, void* d_ws, size_t ws_size,
                              hipStream_t stream)
{
  const float* input = (const float*)d_in[0];
  const float* W_f  = (const float*)d_in[1];
  const float* Wm_f = (const float*)d_in[2];
  const float* U_f  = (const float*)d_in[3];
  const float* Um_f = (const float*)d_in[4];
  const float* b_f  = (const float*)d_in[5];
  const float* U_i  = (const float*)d_in[8];
  const float* Um_i = (const float*)d_in[9];
  const float* W_o  = (const float*)d_in[11];
  const float* Wm_o = (const float*)d_in[12];
  const float* U_o  = (const float*)d_in[13];
  const float* Um_o = (const float*)d_in[14];
  const float* b_o  = (const float*)d_in[15];
  const float* W_c  = (const float*)d_in[16];
  const float* Wm_c = (const float*)d_in[17];
  const float* U_c  = (const float*)d_in[18];
  const float* Um_c = (const float*)d_in[19];
  const float* b_c  = (const float*)d_in[20];

  char* ws = (char*)d_ws;
  size_t off = 0;
  unsigned short* mlx = (unsigned short*)(ws + off); off += (size_t)256 * 3 * 1024 * 64 * 2; // 100.7 MB
  float* hhist = (float*)(ws + off);                 off += (size_t)256 * 1024 * 64 * 4;     //  67.1 MB
  float* cfin  = (float*)(ws + off);                 off += (size_t)1024 * 64 * 4;
  size_t zoff = off;
  unsigned short* hbuf = (unsigned short*)(ws + off); off += (size_t)2 * 8 * 64 * 1024 * 2;  //   2.1 MB
  unsigned int* ctr = (unsigned int*)(ws + off);      off += 256 * 4;
  if (off > ws_size) return;  // insufficient workspace: bail cleanly

  hipMemsetAsync(ws + zoff, 0, off - zoff, stream);  // zero h0 + barrier counters

  xproj_kernel<<<dim3(8, 3, 64), 512, 0, stream>>>(input, W_f, Wm_f, W_o, Wm_o, W_c, Wm_c, mlx);
  recur_kernel<<<256, 256, 0, stream>>>(U_f, Um_f, U_o, Um_o, U_c, Um_c, U_i, Um_i,
                                        b_f, b_o, b_c, mlx, hbuf, hhist, cfin, ctr);
  transpose_kernel<<<dim3(256, 16), 256, 0, stream>>>(hhist, (float*)d_out);
  finals_kernel<<<256, 256, 0, stream>>>(hhist, cfin, (float*)d_out);
}

// Round 2
// 2738.659 us; speedup vs baseline: 3.2029x; 3.2029x over previous
//
#include <hip/hip_runtime.h>
#include <hip/hip_bf16.h>

// GatedLSTM: B=64, T=256, IN=512, H=1024. i-gate computed-but-unused in the
// reference -> dropped entirely. Recurrent exchange uses unique-address
// rotation (hx[t]) so cross-XCD L2 non-coherence needs NO per-step fences.

typedef __attribute__((ext_vector_type(8))) short bfrag;   // 8 x bf16 (4 VGPR)
typedef __attribute__((ext_vector_type(4))) float f32x4;   // MFMA accumulator

__device__ __forceinline__ unsigned short f2b(float v) {
  __hip_bfloat16 h = __float2bfloat16(v);
  union { __hip_bfloat16 h; unsigned short u; } c; c.h = h; return c.u;
}
__device__ __forceinline__ float b2f(unsigned short u) {
  union { unsigned int i; float f; } c; c.i = ((unsigned int)u) << 16; return c.f;
}
__device__ __forceinline__ float sigm(float x) { return 1.0f / (1.0f + __expf(-x)); }
__device__ __forceinline__ float tanh_f(float x) {
  float e = __expf(2.0f * x);
  return (e - 1.0f) / (e + 1.0f);
}

// ---------------------------------------------------------------------------
// Phase 1: x-projections (unchanged from round 1). mlx[t][g][j][b] bf16.
// ---------------------------------------------------------------------------
__global__ __launch_bounds__(512, 2) void xproj_kernel(
    const float* __restrict__ inp,
    const float* __restrict__ Wf, const float* __restrict__ Wmf,
    const float* __restrict__ Wo, const float* __restrict__ Wmo,
    const float* __restrict__ Wc, const float* __restrict__ Wmc,
    unsigned short* __restrict__ mlx)
{
  __shared__ unsigned short Al[256 * 128];  // 64 KB, XOR-swizzled rows
  __shared__ unsigned short Bl[256 * 128];  // 64 KB

  const int tid = threadIdx.x;
  const int w = tid >> 6, l = tid & 63;
  const int c = l & 15, g4 = l >> 4;
  const int jc = blockIdx.x, gate = blockIdx.y, tq = blockIdx.z;
  const float* W  = (gate == 0) ? Wf  : (gate == 1) ? Wo  : Wc;
  const float* Wm = (gate == 0) ? Wmf : (gate == 1) ? Wmo : Wmc;
  const int j0 = jc * 128;

  f32x4 acc[2][16];
#pragma unroll
  for (int mi = 0; mi < 2; ++mi)
#pragma unroll
    for (int ni = 0; ni < 16; ++ni) acc[mi][ni] = (f32x4){0.f, 0.f, 0.f, 0.f};

  for (int kc = 0; kc < 4; ++kc) {
#pragma unroll
    for (int i = 0; i < 16; ++i) {
      int idx = tid + i * 512;      // 0..8191
      int row = idx >> 5;           // 0..255
      int xl  = idx & 31;           // 16B unit within 128-float chunk
      int b_ = row & 63, tl = row >> 6;
      const float4 va = *(const float4*)(inp + (size_t)(b_ * 256 + tq * 4 + tl) * 512 + kc * 128 + xl * 4);
      ushort4 pa;
      pa.x = f2b(va.x); pa.y = f2b(va.y); pa.z = f2b(va.z); pa.w = f2b(va.w);
      *(ushort4*)((char*)Al + ((row * 256 + xl * 8) ^ ((row & 7) << 4))) = pa;
      const float* src = (row < 128) ? (W + (size_t)(j0 + row) * 512)
                                     : (Wm + (size_t)(j0 + row - 128) * 512);
      const float4 vb = *(const float4*)(src + kc * 128 + xl * 4);
      ushort4 pb;
      pb.x = f2b(vb.x); pb.y = f2b(vb.y); pb.z = f2b(vb.z); pb.w = f2b(vb.w);
      *(ushort4*)((char*)Bl + ((row * 256 + xl * 8) ^ ((row & 7) << 4))) = pb;
    }
    __syncthreads();
#pragma unroll
    for (int ks = 0; ks < 4; ++ks) {
      const int koff = (ks * 32 + g4 * 8) * 2;
      bfrag af[2];
#pragma unroll
      for (int mi = 0; mi < 2; ++mi) {
        int row = w * 32 + mi * 16 + c;
        af[mi] = *(const bfrag*)((const char*)Al + ((row * 256 + koff) ^ ((row & 7) << 4)));
      }
#pragma unroll
      for (int ni = 0; ni < 16; ++ni) {
        int n = ni * 16 + c;
        bfrag bf = *(const bfrag*)((const char*)Bl + ((n * 256 + koff) ^ ((n & 7) << 4)));
#pragma unroll
        for (int mi = 0; mi < 2; ++mi)
          acc[mi][ni] = __builtin_amdgcn_mfma_f32_16x16x32_bf16(af[mi], bf, acc[mi][ni], 0, 0, 0);
      }
    }
    __syncthreads();
  }
#pragma unroll
  for (int mi = 0; mi < 2; ++mi) {
#pragma unroll
    for (int ni = 0; ni < 8; ++ni) {
      f32x4 xw = acc[mi][ni];
      f32x4 xm = acc[mi][ni + 8];
      ushort4 st;
      st.x = f2b(xw[0] * sigm(xm[0]));
      st.y = f2b(xw[1] * sigm(xm[1]));
      st.z = f2b(xw[2] * sigm(xm[2]));
      st.w = f2b(xw[3] * sigm(xm[3]));
      int row = w * 32 + mi * 16 + g4 * 4;
      int tl = row >> 6, b_ = row & 63;
      int j = j0 + ni * 16 + c;
      size_t addr = ((size_t)((tq * 4 + tl) * 3 + gate) * 1024 + j) * 64 + b_;
      *(ushort4*)(mlx + addr) = st;
    }
  }
}

// ---------------------------------------------------------------------------
// Phase 2: persistent recurrent kernel. 128 blocks x 256 threads, 1 block/CU
// (150 KB LDS). Block owns h-cols j0=8*bid..+8; 6 U-matrices (48 rows x 1024)
// resident in LDS. Per step: 4-wave K-split MFMA (A = cached hx[t] reads),
// LDS partial reduce, gates, h written to the UNIQUE buffer hx[t+1] via
// relaxed agent atomics (write-through to MALL). Barrier: relaxed agent
// atomic counter, NO fences (unique addresses -> no stale-line hazard).
// ---------------------------------------------------------------------------
__global__ __launch_bounds__(256, 1) void recur_kernel(
    const float* __restrict__ Uf, const float* __restrict__ Umf,
    const float* __restrict__ Uo, const float* __restrict__ Umo,
    const float* __restrict__ Uc, const float* __restrict__ Umc,
    const float* __restrict__ bfp, const float* __restrict__ bop,
    const float* __restrict__ bcp,
    const unsigned short* __restrict__ mlx,  // [256][3][1024][64] bf16
    unsigned short* __restrict__ hx,         // [257][64][1024] bf16
    float* __restrict__ cfin,                // [1024][64] f32
    unsigned int* __restrict__ ctr)          // [256]
{
  __shared__ unsigned short Blds[48 * 1024];   // 96 KB, XOR-swizzled
  __shared__ float prep[4 * 48 * 68];          // 52 KB partials [w][col][row]

  // One-time L1+L2 invalidate: discards poison-epoch / cross-replay lines.
  __builtin_amdgcn_fence(__ATOMIC_ACQUIRE, "agent");

  const int tid = threadIdx.x;
  const int bid = blockIdx.x;
  const int w = tid >> 6, l = tid & 63;
  const int c = l & 15, g4 = l >> 4;
  const int j0 = bid * 8;

  // one-time U stage: row r = mat*8 + cl; mats {Uf,Umf,Uo,Umo,Uc,Umc}
  {
    const float* mats[6] = {Uf, Umf, Uo, Umo, Uc, Umc};
    const int rbase = tid >> 4;   // 0..15
    const int sub = tid & 15;     // 0..15
#pragma unroll
    for (int rep = 0; rep < 3; ++rep) {
      int r = rep * 16 + rbase;
      const float* src = mats[r >> 3] + (size_t)(j0 + (r & 7)) * 1024;
#pragma unroll
      for (int i = 0; i < 16; ++i) {
        int k = sub * 64 + i * 4;
        float4 v = *(const float4*)(src + k);
        ushort4 p;
        p.x = f2b(v.x); p.y = f2b(v.y); p.z = f2b(v.z); p.w = f2b(v.w);
        *(ushort4*)((char*)Blds + (((r * 1024 + k) * 2) ^ ((r & 7) << 4))) = p;
      }
    }
  }

  const int jh = tid >> 6;        // 0..3
  const int bb = tid & 63;
  const int cl0 = jh * 2;         // this thread's 2 adjacent cols
  float bias[2][3], cr[2] = {0.f, 0.f};
  float mf[2], mo[2], mc[2];
#pragma unroll
  for (int q = 0; q < 2; ++q) {
    bias[q][0] = bfp[j0 + cl0 + q];
    bias[q][1] = bop[j0 + cl0 + q];
    bias[q][2] = bcp[j0 + cl0 + q];
  }
  {
    size_t mb = (size_t)(j0 + cl0) * 64 + bb;
#pragma unroll
    for (int q = 0; q < 2; ++q) {
      mf[q] = b2f(mlx[mb + q * 64]);
      mo[q] = b2f(mlx[mb + 65536 + q * 64]);
      mc[q] = b2f(mlx[mb + 2 * 65536 + q * 64]);
    }
  }
  __syncthreads();

  for (int t = 0; t < 256; ++t) {
    const unsigned short* hr = hx + (size_t)t * 65536;   // [b][k] bf16

    f32x4 acc[4][3];
#pragma unroll
    for (int mi = 0; mi < 4; ++mi)
#pragma unroll
      for (int nt = 0; nt < 3; ++nt) acc[mi][nt] = (f32x4){0.f, 0.f, 0.f, 0.f};

#pragma unroll
    for (int ks = 0; ks < 8; ++ks) {
      const int k = w * 256 + ks * 32 + g4 * 8;   // wave-private K slice
      bfrag bfr[3];
#pragma unroll
      for (int nt = 0; nt < 3; ++nt) {
        int n = nt * 16 + c;
        bfr[nt] = *(const bfrag*)((const char*)Blds + (((n * 1024 + k) * 2) ^ ((n & 7) << 4)));
      }
#pragma unroll
      for (int mi = 0; mi < 4; ++mi) {
        const bfrag af = *(const bfrag*)(hr + (size_t)(mi * 16 + c) * 1024 + k);
#pragma unroll
        for (int nt = 0; nt < 3; ++nt)
          acc[mi][nt] = __builtin_amdgcn_mfma_f32_16x16x32_bf16(af, bfr[nt], acc[mi][nt], 0, 0, 0);
      }
    }
#pragma unroll
    for (int mi = 0; mi < 4; ++mi)
#pragma unroll
      for (int nt = 0; nt < 3; ++nt) {
        int col = nt * 16 + c;
        *(f32x4*)&prep[(w * 48 + col) * 68 + mi * 16 + g4 * 4] = acc[mi][nt];
      }
    __syncthreads();

    unsigned int pack = 0;
#pragma unroll
    for (int q = 0; q < 2; ++q) {
      const int cl = cl0 + q;
      float s[6];
#pragma unroll
      for (int m = 0; m < 6; ++m) {
        const int col = m * 8 + cl;
        s[m] = prep[col * 68 + bb] + prep[(48 + col) * 68 + bb] +
               prep[(96 + col) * 68 + bb] + prep[(144 + col) * 68 + bb];
      }
      float fg = sigm(mf[q] + sigm(s[1]) * s[0] + bias[q][0]);
      float og = sigm(mo[q] + sigm(s[3]) * s[2] + bias[q][1]);
      float cd = tanh_f(mc[q] + sigm(s[5]) * s[4] + bias[q][2]);
      cr[q] = fg * cr[q] + cd;
      float hv = og * cr[q];
      pack |= (unsigned int)f2b(hv) << (16 * q);
      if (t == 255) cfin[(size_t)(j0 + cl) * 64 + bb] = cr[q];
    }
    // h -> unique next-step buffer, write-through to MALL (agent-visible)
    __hip_atomic_store((unsigned int*)(hx + (size_t)(t + 1) * 65536 + (size_t)bb * 1024 + j0 + cl0),
                       pack, __ATOMIC_RELAXED, __HIP_MEMORY_SCOPE_AGENT);
    __syncthreads();   // per-wave vmcnt(0) drain: h stores acked before counter

    if (t < 255) {
      // prefetch next step's mlx during the barrier wait
      size_t mb = (size_t)(t + 1) * 3 * 65536 + (size_t)(j0 + cl0) * 64 + bb;
#pragma unroll
      for (int q = 0; q < 2; ++q) {
        mf[q] = b2f(mlx[mb + q * 64]);
        mo[q] = b2f(mlx[mb + 65536 + q * 64]);
        mc[q] = b2f(mlx[mb + 2 * 65536 + q * 64]);
      }
      if (tid == 0) {
        __hip_atomic_fetch_add(&ctr[t], 1u, __ATOMIC_RELAXED, __HIP_MEMORY_SCOPE_AGENT);
        while (__hip_atomic_load(&ctr[t], __ATOMIC_RELAXED, __HIP_MEMORY_SCOPE_AGENT) < 128u)
          __builtin_amdgcn_s_sleep(2);
      }
      __syncthreads();
      asm volatile("" ::: "memory");
    }
  }
}

// ---------------------------------------------------------------------------
// Phase 3: hx [t+1][b][j] bf16 -> out [b][t][j] f32 (pure streaming cast)
// ---------------------------------------------------------------------------
__global__ __launch_bounds__(256) void histcast_kernel(
    const unsigned short* __restrict__ hx, float* __restrict__ out)
{
  const int b = blockIdx.x >> 8, t = blockIdx.x & 255;
  const unsigned short* src = hx + ((size_t)(t + 1) * 64 + b) * 1024;
  float* dst = out + ((size_t)b * 256 + t) * 1024;
  const int j = threadIdx.x * 4;
  ushort4 v = *(const ushort4*)(src + j);
  float4 o;
  o.x = b2f(v.x); o.y = b2f(v.y); o.z = b2f(v.z); o.w = b2f(v.w);
  *(float4*)(dst + j) = o;
}

__global__ __launch_bounds__(256) void finals_kernel(
    const unsigned short* __restrict__ hx, const float* __restrict__ cfin,
    float* __restrict__ out)
{
  int tid = blockIdx.x * 256 + threadIdx.x;  // 0..65535 = b*1024 + j
  int b = tid >> 10, j = tid & 1023;
  out[16777216 + tid]         = b2f(hx[(size_t)256 * 65536 + (size_t)b * 1024 + j]);  // hT
  out[16777216 + 65536 + tid] = cfin[(size_t)j * 64 + b];                             // cT
}

// ---------------------------------------------------------------------------
extern "C" void kernel_launch(void* const* d_in, const int* in_sizes, int n_in,
                              void* d_out, int out_size, void* d_ws, size_t ws_size,
                              hipStream_t stream)
{
  const float* input = (const float*)d_in[0];
  const float* W_f  = (const float*)d_in[1];
  const float* Wm_f = (const float*)d_in[2];
  const float* U_f  = (const float*)d_in[3];
  const float* Um_f = (const float*)d_in[4];
  const float* b_f  = (const float*)d_in[5];
  const float* W_o  = (const float*)d_in[11];
  const float* Wm_o = (const float*)d_in[12];
  const float* U_o  = (const float*)d_in[13];
  const float* Um_o = (const float*)d_in[14];
  const float* b_o  = (const float*)d_in[15];
  const float* W_c  = (const float*)d_in[16];
  const float* Wm_c = (const float*)d_in[17];
  const float* U_c  = (const float*)d_in[18];
  const float* Um_c = (const float*)d_in[19];
  const float* b_c  = (const float*)d_in[20];

  char* ws = (char*)d_ws;
  size_t off = 0;
  unsigned short* mlx = (unsigned short*)(ws + off); off += (size_t)256 * 3 * 1024 * 64 * 2; // 100.7 MB
  unsigned short* hx  = (unsigned short*)(ws + off); off += (size_t)257 * 64 * 1024 * 2;     //  33.7 MB
  float* cfin = (float*)(ws + off);                  off += (size_t)1024 * 64 * 4;
  unsigned int* ctr = (unsigned int*)(ws + off);     off += 256 * 4;
  if (off > ws_size) return;  // insufficient workspace: bail cleanly

  hipMemsetAsync(hx, 0, 131072, stream);   // h0 = 0
  hipMemsetAsync(ctr, 0, 1024, stream);    // barrier counters

  xproj_kernel<<<dim3(8, 3, 64), 512, 0, stream>>>(input, W_f, Wm_f, W_o, Wm_o, W_c, Wm_c, mlx);
  recur_kernel<<<128, 256, 0, stream>>>(U_f, Um_f, U_o, Um_o, U_c, Um_c,
                                        b_f, b_o, b_c, mlx, hx, cfin, ctr);
  histcast_kernel<<<16384, 256, 0, stream>>>(hx, (float*)d_out);
  finals_kernel<<<256, 256, 0, stream>>>(hx, cfin, (float*)d_out);
}

// Round 3
// 2341.032 us; speedup vs baseline: 3.7469x; 1.1699x over previous
//
#include <hip/hip_runtime.h>
#include <hip/hip_bf16.h>

// GatedLSTM: B=64, T=256, IN=512, H=1024. i-gate computed-but-unused in the
// reference -> dropped entirely. Recurrent exchange uses unique-address
// rotation (hx[t]) + per-producer dataflow flags: no atomics, no fences,
// no global barrier. Wave w of every block waits only on the 32 producer
// blocks of its K-slice.

typedef __attribute__((ext_vector_type(8))) short bfrag;   // 8 x bf16 (4 VGPR)
typedef __attribute__((ext_vector_type(4))) float f32x4;   // MFMA accumulator

__device__ __forceinline__ unsigned short f2b(float v) {
  __hip_bfloat16 h = __float2bfloat16(v);
  union { __hip_bfloat16 h; unsigned short u; } c; c.h = h; return c.u;
}
__device__ __forceinline__ float b2f(unsigned short u) {
  union { unsigned int i; float f; } c; c.i = ((unsigned int)u) << 16; return c.f;
}
__device__ __forceinline__ float sigm(float x) { return 1.0f / (1.0f + __expf(-x)); }
__device__ __forceinline__ float tanh_f(float x) {
  float e = __expf(2.0f * x);
  return (e - 1.0f) / (e + 1.0f);
}

// ---------------------------------------------------------------------------
// Phase 1: x-projections (unchanged). mlx[t][g][j][b] bf16.
// ---------------------------------------------------------------------------
__global__ __launch_bounds__(512, 2) void xproj_kernel(
    const float* __restrict__ inp,
    const float* __restrict__ Wf, const float* __restrict__ Wmf,
    const float* __restrict__ Wo, const float* __restrict__ Wmo,
    const float* __restrict__ Wc, const float* __restrict__ Wmc,
    unsigned short* __restrict__ mlx)
{
  __shared__ unsigned short Al[256 * 128];  // 64 KB, XOR-swizzled rows
  __shared__ unsigned short Bl[256 * 128];  // 64 KB

  const int tid = threadIdx.x;
  const int w = tid >> 6, l = tid & 63;
  const int c = l & 15, g4 = l >> 4;
  const int jc = blockIdx.x, gate = blockIdx.y, tq = blockIdx.z;
  const float* W  = (gate == 0) ? Wf  : (gate == 1) ? Wo  : Wc;
  const float* Wm = (gate == 0) ? Wmf : (gate == 1) ? Wmo : Wmc;
  const int j0 = jc * 128;

  f32x4 acc[2][16];
#pragma unroll
  for (int mi = 0; mi < 2; ++mi)
#pragma unroll
    for (int ni = 0; ni < 16; ++ni) acc[mi][ni] = (f32x4){0.f, 0.f, 0.f, 0.f};

  for (int kc = 0; kc < 4; ++kc) {
#pragma unroll
    for (int i = 0; i < 16; ++i) {
      int idx = tid + i * 512;      // 0..8191
      int row = idx >> 5;           // 0..255
      int xl  = idx & 31;           // 16B unit within 128-float chunk
      int b_ = row & 63, tl = row >> 6;
      const float4 va = *(const float4*)(inp + (size_t)(b_ * 256 + tq * 4 + tl) * 512 + kc * 128 + xl * 4);
      ushort4 pa;
      pa.x = f2b(va.x); pa.y = f2b(va.y); pa.z = f2b(va.z); pa.w = f2b(va.w);
      *(ushort4*)((char*)Al + ((row * 256 + xl * 8) ^ ((row & 7) << 4))) = pa;
      const float* src = (row < 128) ? (W + (size_t)(j0 + row) * 512)
                                     : (Wm + (size_t)(j0 + row - 128) * 512);
      const float4 vb = *(const float4*)(src + kc * 128 + xl * 4);
      ushort4 pb;
      pb.x = f2b(vb.x); pb.y = f2b(vb.y); pb.z = f2b(vb.z); pb.w = f2b(vb.w);
      *(ushort4*)((char*)Bl + ((row * 256 + xl * 8) ^ ((row & 7) << 4))) = pb;
    }
    __syncthreads();
#pragma unroll
    for (int ks = 0; ks < 4; ++ks) {
      const int koff = (ks * 32 + g4 * 8) * 2;
      bfrag af[2];
#pragma unroll
      for (int mi = 0; mi < 2; ++mi) {
        int row = w * 32 + mi * 16 + c;
        af[mi] = *(const bfrag*)((const char*)Al + ((row * 256 + koff) ^ ((row & 7) << 4)));
      }
#pragma unroll
      for (int ni = 0; ni < 16; ++ni) {
        int n = ni * 16 + c;
        bfrag bf = *(const bfrag*)((const char*)Bl + ((n * 256 + koff) ^ ((n & 7) << 4)));
#pragma unroll
        for (int mi = 0; mi < 2; ++mi)
          acc[mi][ni] = __builtin_amdgcn_mfma_f32_16x16x32_bf16(af[mi], bf, acc[mi][ni], 0, 0, 0);
      }
    }
    __syncthreads();
  }
#pragma unroll
  for (int mi = 0; mi < 2; ++mi) {
#pragma unroll
    for (int ni = 0; ni < 8; ++ni) {
      f32x4 xw = acc[mi][ni];
      f32x4 xm = acc[mi][ni + 8];
      ushort4 st;
      st.x = f2b(xw[0] * sigm(xm[0]));
      st.y = f2b(xw[1] * sigm(xm[1]));
      st.z = f2b(xw[2] * sigm(xm[2]));
      st.w = f2b(xw[3] * sigm(xm[3]));
      int row = w * 32 + mi * 16 + g4 * 4;
      int tl = row >> 6, b_ = row & 63;
      int j = j0 + ni * 16 + c;
      size_t addr = ((size_t)((tq * 4 + tl) * 3 + gate) * 1024 + j) * 64 + b_;
      *(ushort4*)(mlx + addr) = st;
    }
  }
}

// ---------------------------------------------------------------------------
// Phase 2: persistent recurrent kernel, dataflow-synced. 128 blocks x 256
// threads. Block owns h-cols j0=8*bid..+8. U (6 mats x 8 rows, bf16) lives in
// REGISTERS (each wave holds its K-slice: 24 bfrags = 96 VGPR). Per step:
//   wave w polls flags of producers 32w..32w+31, MFMAs its K-slice,
//   cross-wave reduce via LDS, gates, h -> unique hx[t+1] (agent atomics),
//   vmcnt drain via __syncthreads, then sets flg[t+1][bid].
// ---------------------------------------------------------------------------
__global__ __launch_bounds__(256, 1) void recur_kernel(
    const float* __restrict__ Uf, const float* __restrict__ Umf,
    const float* __restrict__ Uo, const float* __restrict__ Umo,
    const float* __restrict__ Uc, const float* __restrict__ Umc,
    const float* __restrict__ bfp, const float* __restrict__ bop,
    const float* __restrict__ bcp,
    const unsigned short* __restrict__ mlx,  // [256][3][1024][64] bf16
    unsigned short* __restrict__ hx,         // [257][64][1024] bf16
    float* __restrict__ cfin,                // [1024][64] f32
    unsigned int* __restrict__ flg)          // [257][128]
{
  __shared__ float prep[4 * 48 * 68];        // 52 KB partials [w][col][row]

  // One-time L1+L2 invalidate: discards poison-epoch / cross-replay lines.
  __builtin_amdgcn_fence(__ATOMIC_ACQUIRE, "agent");

  const int tid = threadIdx.x;
  const int bid = blockIdx.x;
  const int w = tid >> 6, l = tid & 63;
  const int c = l & 15, g4 = l >> 4;
  const int j0 = bid * 8;

  // ---- one-time U stage into registers: Breg[nt][ks] -------------------
  bfrag Breg[3][8];
#pragma unroll
  for (int nt = 0; nt < 3; ++nt) {
    const int n = nt * 16 + c;          // 0..47
    const int mi6 = n >> 3;             // 0..5 (ternary chain: no scratch)
    const float* src = (mi6 == 0) ? Uf : (mi6 == 1) ? Umf : (mi6 == 2) ? Uo
                     : (mi6 == 3) ? Umo : (mi6 == 4) ? Uc : Umc;
    src += (size_t)(j0 + (n & 7)) * 1024;
#pragma unroll
    for (int ks = 0; ks < 8; ++ks) {
      const int k = w * 256 + ks * 32 + g4 * 8;
      const float4 v0 = *(const float4*)(src + k);
      const float4 v1 = *(const float4*)(src + k + 4);
      bfrag b;
      b[0] = (short)f2b(v0.x); b[1] = (short)f2b(v0.y);
      b[2] = (short)f2b(v0.z); b[3] = (short)f2b(v0.w);
      b[4] = (short)f2b(v1.x); b[5] = (short)f2b(v1.y);
      b[6] = (short)f2b(v1.z); b[7] = (short)f2b(v1.w);
      Breg[nt][ks] = b;
    }
  }

  const int jh = tid >> 6;        // 0..3
  const int bb = tid & 63;
  const int cl0 = jh * 2;         // this thread's 2 adjacent cols
  float bias[2][3], cr[2] = {0.f, 0.f};
  float mf[2], mo[2], mc[2];
#pragma unroll
  for (int q = 0; q < 2; ++q) {
    bias[q][0] = bfp[j0 + cl0 + q];
    bias[q][1] = bop[j0 + cl0 + q];
    bias[q][2] = bcp[j0 + cl0 + q];
  }
  {
    size_t mb = (size_t)(j0 + cl0) * 64 + bb;
#pragma unroll
    for (int q = 0; q < 2; ++q) {
      mf[q] = b2f(mlx[mb + q * 64]);
      mo[q] = b2f(mlx[mb + 65536 + q * 64]);
      mc[q] = b2f(mlx[mb + 2 * 65536 + q * 64]);
    }
  }

  for (int t = 0; t < 256; ++t) {
    // ---- dataflow wait: wave w needs producers 32w..32w+31 of hx[t] ----
    if (t > 0) {
      const unsigned int* fp = flg + (size_t)t * 128 + w * 32 + l;
      unsigned int v = 1;
      while (true) {
        if (l < 32) v = __hip_atomic_load(fp, __ATOMIC_RELAXED, __HIP_MEMORY_SCOPE_AGENT);
        if (__all(v != 0)) break;
        __builtin_amdgcn_s_sleep(1);
      }
      asm volatile("" ::: "memory");   // keep h loads below the poll
    }
    const unsigned short* hr = hx + (size_t)t * 65536;   // [b][k] bf16

    f32x4 acc[4][3];
#pragma unroll
    for (int mi = 0; mi < 4; ++mi)
#pragma unroll
      for (int nt = 0; nt < 3; ++nt) acc[mi][nt] = (f32x4){0.f, 0.f, 0.f, 0.f};

#pragma unroll
    for (int ks = 0; ks < 8; ++ks) {
      const int k = w * 256 + ks * 32 + g4 * 8;   // wave-private K slice
#pragma unroll
      for (int mi = 0; mi < 4; ++mi) {
        const bfrag af = *(const bfrag*)(hr + (size_t)(mi * 16 + c) * 1024 + k);
#pragma unroll
        for (int nt = 0; nt < 3; ++nt)
          acc[mi][nt] = __builtin_amdgcn_mfma_f32_16x16x32_bf16(af, Breg[nt][ks], acc[mi][nt], 0, 0, 0);
      }
    }
#pragma unroll
    for (int mi = 0; mi < 4; ++mi)
#pragma unroll
      for (int nt = 0; nt < 3; ++nt) {
        int col = nt * 16 + c;
        *(f32x4*)&prep[(w * 48 + col) * 68 + mi * 16 + g4 * 4] = acc[mi][nt];
      }
    __syncthreads();

    unsigned int pack = 0;
#pragma unroll
    for (int q = 0; q < 2; ++q) {
      const int cl = cl0 + q;
      float s[6];
#pragma unroll
      for (int m = 0; m < 6; ++m) {
        const int col = m * 8 + cl;
        s[m] = prep[col * 68 + bb] + prep[(48 + col) * 68 + bb] +
               prep[(96 + col) * 68 + bb] + prep[(144 + col) * 68 + bb];
      }
      float fg = sigm(mf[q] + sigm(s[1]) * s[0] + bias[q][0]);
      float og = sigm(mo[q] + sigm(s[3]) * s[2] + bias[q][1]);
      float cd = tanh_f(mc[q] + sigm(s[5]) * s[4] + bias[q][2]);
      cr[q] = fg * cr[q] + cd;
      float hv = og * cr[q];
      pack |= (unsigned int)f2b(hv) << (16 * q);
      if (t == 255) cfin[(size_t)(j0 + cl) * 64 + bb] = cr[q];
    }
    // h -> unique next-step buffer, write-through to MALL (agent-visible)
    __hip_atomic_store((unsigned int*)(hx + (size_t)(t + 1) * 65536 + (size_t)bb * 1024 + j0 + cl0),
                       pack, __ATOMIC_RELAXED, __HIP_MEMORY_SCOPE_AGENT);
    __syncthreads();   // per-wave vmcnt(0) drain before barrier: h stores acked

    if (tid == 0)      // publish: all 4 waves' h stores are at the MALL
      __hip_atomic_store(&flg[(size_t)(t + 1) * 128 + bid], 1u,
                         __ATOMIC_RELAXED, __HIP_MEMORY_SCOPE_AGENT);

    if (t < 255) {
      // prefetch next step's mlx while producers finish
      size_t mb = (size_t)(t + 1) * 3 * 65536 + (size_t)(j0 + cl0) * 64 + bb;
#pragma unroll
      for (int q = 0; q < 2; ++q) {
        mf[q] = b2f(mlx[mb + q * 64]);
        mo[q] = b2f(mlx[mb + 65536 + q * 64]);
        mc[q] = b2f(mlx[mb + 2 * 65536 + q * 64]);
      }
    }
  }
}

// ---------------------------------------------------------------------------
// Phase 3: hx [t+1][b][j] bf16 -> out [b][t][j] f32 (pure streaming cast)
// ---------------------------------------------------------------------------
__global__ __launch_bounds__(256) void histcast_kernel(
    const unsigned short* __restrict__ hx, float* __restrict__ out)
{
  const int b = blockIdx.x >> 8, t = blockIdx.x & 255;
  const unsigned short* src = hx + ((size_t)(t + 1) * 64 + b) * 1024;
  float* dst = out + ((size_t)b * 256 + t) * 1024;
  const int j = threadIdx.x * 4;
  ushort4 v = *(const ushort4*)(src + j);
  float4 o;
  o.x = b2f(v.x); o.y = b2f(v.y); o.z = b2f(v.z); o.w = b2f(v.w);
  *(float4*)(dst + j) = o;
}

__global__ __launch_bounds__(256) void finals_kernel(
    const unsigned short* __restrict__ hx, const float* __restrict__ cfin,
    float* __restrict__ out)
{
  int tid = blockIdx.x * 256 + threadIdx.x;  // 0..65535 = b*1024 + j
  int b = tid >> 10, j = tid & 1023;
  out[16777216 + tid]         = b2f(hx[(size_t)256 * 65536 + (size_t)b * 1024 + j]);  // hT
  out[16777216 + 65536 + tid] = cfin[(size_t)j * 64 + b];                             // cT
}

// ---------------------------------------------------------------------------
extern "C" void kernel_launch(void* const* d_in, const int* in_sizes, int n_in,
                              void* d_out, int out_size, void* d_ws, size_t ws_size,
                              hipStream_t stream)
{
  const float* input = (const float*)d_in[0];
  const float* W_f  = (const float*)d_in[1];
  const float* Wm_f = (const float*)d_in[2];
  const float* U_f  = (const float*)d_in[3];
  const float* Um_f = (const float*)d_in[4];
  const float* b_f  = (const float*)d_in[5];
  const float* W_o  = (const float*)d_in[11];
  const float* Wm_o = (const float*)d_in[12];
  const float* U_o  = (const float*)d_in[13];
  const float* Um_o = (const float*)d_in[14];
  const float* b_o  = (const float*)d_in[15];
  const float* W_c  = (const float*)d_in[16];
  const float* Wm_c = (const float*)d_in[17];
  const float* U_c  = (const float*)d_in[18];
  const float* Um_c = (const float*)d_in[19];
  const float* b_c  = (const float*)d_in[20];

  char* ws = (char*)d_ws;
  size_t off = 0;
  unsigned short* mlx = (unsigned short*)(ws + off); off += (size_t)256 * 3 * 1024 * 64 * 2; // 100.7 MB
  unsigned short* hx  = (unsigned short*)(ws + off); off += (size_t)257 * 64 * 1024 * 2;     //  33.7 MB
  float* cfin = (float*)(ws + off);                  off += (size_t)1024 * 64 * 4;
  unsigned int* flg = (unsigned int*)(ws + off);     off += (size_t)257 * 128 * 4;           // 131.6 KB
  if (off > ws_size) return;  // insufficient workspace: bail cleanly

  hipMemsetAsync(hx, 0, 131072, stream);                 // h0 = 0
  hipMemsetAsync(flg, 0, (size_t)257 * 128 * 4, stream); // dataflow flags

  xproj_kernel<<<dim3(8, 3, 64), 512, 0, stream>>>(input, W_f, Wm_f, W_o, Wm_o, W_c, Wm_c, mlx);
  recur_kernel<<<128, 256, 0, stream>>>(U_f, Um_f, U_o, Um_o, U_c, Um_c,
                                        b_f, b_o, b_c, mlx, hx, cfin, flg);
  histcast_kernel<<<16384, 256, 0, stream>>>(hx, (float*)d_out);
  finals_kernel<<<256, 256, 0, stream>>>(hx, cfin, (float*)d_out);
}

// Round 4
// 2270.783 us; speedup vs baseline: 3.8628x; 1.0309x over previous
//
#include <hip/hip_runtime.h>
#include <hip/hip_bf16.h>

// GatedLSTM: B=64, T=256, IN=512, H=1024. i-gate dead in reference -> dropped.
// Recurrent exchange: unique-address rotation hx[t] (chunk layout) +
// PER-WAVE sentinels. Producer wave: data stores -> s_waitcnt vmcnt(0) ->
// sentinel store (all agent-scope write-through, MALL-ordered). Consumer
// wave w polls only its 32 producer blocks' 4 wave-sentinels (128 dwords,
// one 8B agent load per lane), then reads h with normal cached loads
// (first-touch; line complete at MALL before any fetch => L2 sharing safe).

typedef __attribute__((ext_vector_type(8))) short bfrag;   // 8 x bf16 (4 VGPR)
typedef __attribute__((ext_vector_type(4))) float f32x4;   // MFMA accumulator

__device__ __forceinline__ unsigned short f2b(float v) {
  __hip_bfloat16 h = __float2bfloat16(v);
  union { __hip_bfloat16 h; unsigned short u; } c; c.h = h; return c.u;
}
__device__ __forceinline__ float b2f(unsigned short u) {
  union { unsigned int i; float f; } c; c.i = ((unsigned int)u) << 16; return c.f;
}
__device__ __forceinline__ float sigm(float x) { return 1.0f / (1.0f + __expf(-x)); }
__device__ __forceinline__ float tanh_f(float x) {
  float e = __expf(2.0f * x);
  return (e - 1.0f) / (e + 1.0f);
}

// ---------------------------------------------------------------------------
// Phase 1: x-projections (unchanged). mlx[t][g][j][b] bf16.
// ---------------------------------------------------------------------------
__global__ __launch_bounds__(512, 2) void xproj_kernel(
    const float* __restrict__ inp,
    const float* __restrict__ Wf, const float* __restrict__ Wmf,
    const float* __restrict__ Wo, const float* __restrict__ Wmo,
    const float* __restrict__ Wc, const float* __restrict__ Wmc,
    unsigned short* __restrict__ mlx)
{
  __shared__ unsigned short Al[256 * 128];  // 64 KB, XOR-swizzled rows
  __shared__ unsigned short Bl[256 * 128];  // 64 KB

  const int tid = threadIdx.x;
  const int w = tid >> 6, l = tid & 63;
  const int c = l & 15, g4 = l >> 4;
  const int jc = blockIdx.x, gate = blockIdx.y, tq = blockIdx.z;
  const float* W  = (gate == 0) ? Wf  : (gate == 1) ? Wo  : Wc;
  const float* Wm = (gate == 0) ? Wmf : (gate == 1) ? Wmo : Wmc;
  const int j0 = jc * 128;

  f32x4 acc[2][16];
#pragma unroll
  for (int mi = 0; mi < 2; ++mi)
#pragma unroll
    for (int ni = 0; ni < 16; ++ni) acc[mi][ni] = (f32x4){0.f, 0.f, 0.f, 0.f};

  for (int kc = 0; kc < 4; ++kc) {
#pragma unroll
    for (int i = 0; i < 16; ++i) {
      int idx = tid + i * 512;      // 0..8191
      int row = idx >> 5;           // 0..255
      int xl  = idx & 31;           // 16B unit within 128-float chunk
      int b_ = row & 63, tl = row >> 6;
      const float4 va = *(const float4*)(inp + (size_t)(b_ * 256 + tq * 4 + tl) * 512 + kc * 128 + xl * 4);
      ushort4 pa;
      pa.x = f2b(va.x); pa.y = f2b(va.y); pa.z = f2b(va.z); pa.w = f2b(va.w);
      *(ushort4*)((char*)Al + ((row * 256 + xl * 8) ^ ((row & 7) << 4))) = pa;
      const float* src = (row < 128) ? (W + (size_t)(j0 + row) * 512)
                                     : (Wm + (size_t)(j0 + row - 128) * 512);
      const float4 vb = *(const float4*)(src + kc * 128 + xl * 4);
      ushort4 pb;
      pb.x = f2b(vb.x); pb.y = f2b(vb.y); pb.z = f2b(vb.z); pb.w = f2b(vb.w);
      *(ushort4*)((char*)Bl + ((row * 256 + xl * 8) ^ ((row & 7) << 4))) = pb;
    }
    __syncthreads();
#pragma unroll
    for (int ks = 0; ks < 4; ++ks) {
      const int koff = (ks * 32 + g4 * 8) * 2;
      bfrag af[2];
#pragma unroll
      for (int mi = 0; mi < 2; ++mi) {
        int row = w * 32 + mi * 16 + c;
        af[mi] = *(const bfrag*)((const char*)Al + ((row * 256 + koff) ^ ((row & 7) << 4)));
      }
#pragma unroll
      for (int ni = 0; ni < 16; ++ni) {
        int n = ni * 16 + c;
        bfrag bf = *(const bfrag*)((const char*)Bl + ((n * 256 + koff) ^ ((n & 7) << 4)));
#pragma unroll
        for (int mi = 0; mi < 2; ++mi)
          acc[mi][ni] = __builtin_amdgcn_mfma_f32_16x16x32_bf16(af[mi], bf, acc[mi][ni], 0, 0, 0);
      }
    }
    __syncthreads();
  }
#pragma unroll
  for (int mi = 0; mi < 2; ++mi) {
#pragma unroll
    for (int ni = 0; ni < 8; ++ni) {
      f32x4 xw = acc[mi][ni];
      f32x4 xm = acc[mi][ni + 8];
      ushort4 st;
      st.x = f2b(xw[0] * sigm(xm[0]));
      st.y = f2b(xw[1] * sigm(xm[1]));
      st.z = f2b(xw[2] * sigm(xm[2]));
      st.w = f2b(xw[3] * sigm(xm[3]));
      int row = w * 32 + mi * 16 + g4 * 4;
      int tl = row >> 6, b_ = row & 63;
      int j = j0 + ni * 16 + c;
      size_t addr = ((size_t)((tq * 4 + tl) * 3 + gate) * 1024 + j) * 64 + b_;
      *(ushort4*)(mlx + addr) = st;
    }
  }
}

// ---------------------------------------------------------------------------
// Phase 2: persistent recurrent kernel, per-wave dataflow sync. 128 blocks x
// 256 threads, 1 block/CU (104 KB LDS). Block owns h-cols j0=8*bid..+8.
// hx chunk layout: hx[t][kb][b][8] bf16 (kb = k>>3; block bid writes kb=bid).
// Per step per wave: sentinel poll (32 producers x 4 waves) -> MFMA K-slice
// (normal cached h loads) -> ds_write partials (double-buffered) -> barrier
// -> gates -> h dword stores (agent) -> s_waitcnt vmcnt(0) -> sentinel.
// ---------------------------------------------------------------------------
__global__ __launch_bounds__(256, 1) void recur_kernel(
    const float* __restrict__ Uf, const float* __restrict__ Umf,
    const float* __restrict__ Uo, const float* __restrict__ Umo,
    const float* __restrict__ Uc, const float* __restrict__ Umc,
    const float* __restrict__ bfp, const float* __restrict__ bop,
    const float* __restrict__ bcp,
    const unsigned short* __restrict__ mlx,  // [256][3][1024][64] bf16
    unsigned short* __restrict__ hx,         // [257][128][64][8] bf16
    float* __restrict__ cfin,                // [1024][64] f32
    unsigned int* __restrict__ sent)         // [257][128][4]
{
  __shared__ float prep[2][4 * 48 * 68];     // 2 x 52 KB partials [w][col][row]

  // One-time L1+L2 invalidate: discards poison-epoch / cross-replay lines.
  __builtin_amdgcn_fence(__ATOMIC_ACQUIRE, "agent");

  const int tid = threadIdx.x;
  const int bid = blockIdx.x;
  const int w = tid >> 6, l = tid & 63;
  const int c = l & 15, g4 = l >> 4;
  const int j0 = bid * 8;

  // ---- one-time U stage into registers: Breg[nt][ks] -------------------
  bfrag Breg[3][8];
#pragma unroll
  for (int nt = 0; nt < 3; ++nt) {
    const int n = nt * 16 + c;          // 0..47
    const int mi6 = n >> 3;             // 0..5 (ternary chain: no scratch)
    const float* src = (mi6 == 0) ? Uf : (mi6 == 1) ? Umf : (mi6 == 2) ? Uo
                     : (mi6 == 3) ? Umo : (mi6 == 4) ? Uc : Umc;
    src += (size_t)(j0 + (n & 7)) * 1024;
#pragma unroll
    for (int ks = 0; ks < 8; ++ks) {
      const int k = w * 256 + ks * 32 + g4 * 8;
      const float4 v0 = *(const float4*)(src + k);
      const float4 v1 = *(const float4*)(src + k + 4);
      bfrag b;
      b[0] = (short)f2b(v0.x); b[1] = (short)f2b(v0.y);
      b[2] = (short)f2b(v0.z); b[3] = (short)f2b(v0.w);
      b[4] = (short)f2b(v1.x); b[5] = (short)f2b(v1.y);
      b[6] = (short)f2b(v1.z); b[7] = (short)f2b(v1.w);
      Breg[nt][ks] = b;
    }
  }

  const int bb = l;               // elementwise: b = lane, cols cl0 = 2w
  const int cl0 = w * 2;
  float bias[2][3], cr[2] = {0.f, 0.f};
  float mf[2], mo[2], mc[2];
#pragma unroll
  for (int q = 0; q < 2; ++q) {
    bias[q][0] = bfp[j0 + cl0 + q];
    bias[q][1] = bop[j0 + cl0 + q];
    bias[q][2] = bcp[j0 + cl0 + q];
  }
  {
    size_t mb = (size_t)(j0 + cl0) * 64 + bb;
#pragma unroll
    for (int q = 0; q < 2; ++q) {
      mf[q] = b2f(mlx[mb + q * 64]);
      mo[q] = b2f(mlx[mb + 65536 + q * 64]);
      mc[q] = b2f(mlx[mb + 2 * 65536 + q * 64]);
    }
  }

  for (int t = 0; t < 256; ++t) {
    // ---- per-wave sentinel poll: producers 32w..32w+31, all 4 waves ----
    if (t > 0) {
      const unsigned long long* sp =
          (const unsigned long long*)(sent + (size_t)t * 512 + w * 128 + 2 * l);
      while (true) {
        unsigned long long v = __hip_atomic_load(sp, __ATOMIC_RELAXED, __HIP_MEMORY_SCOPE_AGENT);
        if (__all(v == 0x0000000100000001ULL)) break;
      }
      __builtin_amdgcn_sched_barrier(0);
      asm volatile("" ::: "memory");   // keep h loads below the poll
    }

    f32x4 acc[4][3];
#pragma unroll
    for (int mi = 0; mi < 4; ++mi)
#pragma unroll
      for (int nt = 0; nt < 3; ++nt) acc[mi][nt] = (f32x4){0.f, 0.f, 0.f, 0.f};

#pragma unroll
    for (int ks = 0; ks < 8; ++ks) {
      const int kb = w * 32 + ks * 4 + g4;   // wave-private chunk ids
#pragma unroll
      for (int mi = 0; mi < 4; ++mi) {
        const bfrag af = *(const bfrag*)(hx + (((size_t)t * 128 + kb) * 64 + mi * 16 + c) * 8);
#pragma unroll
        for (int nt = 0; nt < 3; ++nt)
          acc[mi][nt] = __builtin_amdgcn_mfma_f32_16x16x32_bf16(af, Breg[nt][ks], acc[mi][nt], 0, 0, 0);
      }
    }
    float* pp = prep[t & 1];
#pragma unroll
    for (int mi = 0; mi < 4; ++mi)
#pragma unroll
      for (int nt = 0; nt < 3; ++nt) {
        int col = nt * 16 + c;
        *(f32x4*)&pp[(w * 48 + col) * 68 + mi * 16 + g4 * 4] = acc[mi][nt];
      }
    __syncthreads();   // the ONLY per-step barrier (prep double-buffered)

    unsigned int pack = 0;
#pragma unroll
    for (int q = 0; q < 2; ++q) {
      const int cl = cl0 + q;
      float s[6];
#pragma unroll
      for (int m = 0; m < 6; ++m) {
        const int col = m * 8 + cl;
        s[m] = pp[col * 68 + bb] + pp[(48 + col) * 68 + bb] +
               pp[(96 + col) * 68 + bb] + pp[(144 + col) * 68 + bb];
      }
      float fg = sigm(mf[q] + sigm(s[1]) * s[0] + bias[q][0]);
      float og = sigm(mo[q] + sigm(s[3]) * s[2] + bias[q][1]);
      float cd = tanh_f(mc[q] + sigm(s[5]) * s[4] + bias[q][2]);
      cr[q] = fg * cr[q] + cd;
      float hv = og * cr[q];
      pack |= (unsigned int)f2b(hv) << (16 * q);
      if (t == 255) cfin[(size_t)(j0 + cl) * 64 + bb] = cr[q];
    }
    // h dword -> unique chunk hx[t+1][bid][bb][cl0..+1] (agent write-through)
    __hip_atomic_store(
        (unsigned int*)(hx + ((((size_t)(t + 1) * 128 + bid) * 64 + bb) * 8 + cl0)),
        pack, __ATOMIC_RELAXED, __HIP_MEMORY_SCOPE_AGENT);

    // per-WAVE drain: this wave's h stores acked at MALL, then its sentinel
    asm volatile("s_waitcnt vmcnt(0)" ::: "memory");
    if (l == 0)
      __hip_atomic_store(&sent[(size_t)(t + 1) * 512 + bid * 4 + w], 1u,
                         __ATOMIC_RELAXED, __HIP_MEMORY_SCOPE_AGENT);

    if (t < 255) {
      // prefetch next step's mlx; completes during the next sentinel poll
      size_t mb = (size_t)(t + 1) * 3 * 65536 + (size_t)(j0 + cl0) * 64 + bb;
#pragma unroll
      for (int q = 0; q < 2; ++q) {
        mf[q] = b2f(mlx[mb + q * 64]);
        mo[q] = b2f(mlx[mb + 65536 + q * 64]);
        mc[q] = b2f(mlx[mb + 2 * 65536 + q * 64]);
      }
    }
  }
}

// ---------------------------------------------------------------------------
// Phase 3: hx chunks -> out [b][t][j] f32 (streaming cast)
// ---------------------------------------------------------------------------
__global__ __launch_bounds__(128) void histcast_kernel(
    const unsigned short* __restrict__ hx, float* __restrict__ out)
{
  const int b = blockIdx.x >> 8, t = blockIdx.x & 255;
  const int j = threadIdx.x * 8;
  const unsigned short* src = hx + (((size_t)(t + 1) * 128 + (j >> 3)) * 64 + b) * 8;
  float* dst = out + ((size_t)b * 256 + t) * 1024 + j;
  ushort4 v0 = *(const ushort4*)(src);
  ushort4 v1 = *(const ushort4*)(src + 4);
  float4 o0, o1;
  o0.x = b2f(v0.x); o0.y = b2f(v0.y); o0.z = b2f(v0.z); o0.w = b2f(v0.w);
  o1.x = b2f(v1.x); o1.y = b2f(v1.y); o1.z = b2f(v1.z); o1.w = b2f(v1.w);
  *(float4*)(dst) = o0;
  *(float4*)(dst + 4) = o1;
}

__global__ __launch_bounds__(256) void finals_kernel(
    const unsigned short* __restrict__ hx, const float* __restrict__ cfin,
    float* __restrict__ out)
{
  int tid = blockIdx.x * 256 + threadIdx.x;  // 0..65535 = b*1024 + j
  int b = tid >> 10, j = tid & 1023;
  out[16777216 + tid]         = b2f(hx[(((size_t)256 * 128 + (j >> 3)) * 64 + b) * 8 + (j & 7)]);
  out[16777216 + 65536 + tid] = cfin[(size_t)j * 64 + b];
}

// ---------------------------------------------------------------------------
extern "C" void kernel_launch(void* const* d_in, const int* in_sizes, int n_in,
                              void* d_out, int out_size, void* d_ws, size_t ws_size,
                              hipStream_t stream)
{
  const float* input = (const float*)d_in[0];
  const float* W_f  = (const float*)d_in[1];
  const float* Wm_f = (const float*)d_in[2];
  const float* U_f  = (const float*)d_in[3];
  const float* Um_f = (const float*)d_in[4];
  const float* b_f  = (const float*)d_in[5];
  const float* W_o  = (const float*)d_in[11];
  const float* Wm_o = (const float*)d_in[12];
  const float* U_o  = (const float*)d_in[13];
  const float* Um_o = (const float*)d_in[14];
  const float* b_o  = (const float*)d_in[15];
  const float* W_c  = (const float*)d_in[16];
  const float* Wm_c = (const float*)d_in[17];
  const float* U_c  = (const float*)d_in[18];
  const float* Um_c = (const float*)d_in[19];
  const float* b_c  = (const float*)d_in[20];

  char* ws = (char*)d_ws;
  size_t off = 0;
  unsigned short* mlx = (unsigned short*)(ws + off); off += (size_t)256 * 3 * 1024 * 64 * 2; // 100.7 MB
  unsigned short* hx  = (unsigned short*)(ws + off); off += (size_t)257 * 128 * 64 * 8 * 2;  //  33.7 MB
  float* cfin = (float*)(ws + off);                  off += (size_t)1024 * 64 * 4;
  unsigned int* sent = (unsigned int*)(ws + off);    off += (size_t)257 * 512 * 4;           // 526 KB
  if (off > ws_size) return;  // insufficient workspace: bail cleanly

  hipMemsetAsync(hx, 0, 131072, stream);                  // h0 = 0 (chunk step 0)
  hipMemsetAsync(sent, 0, (size_t)257 * 512 * 4, stream); // sentinels

  xproj_kernel<<<dim3(8, 3, 64), 512, 0, stream>>>(input, W_f, Wm_f, W_o, Wm_o, W_c, Wm_c, mlx);
  recur_kernel<<<128, 256, 0, stream>>>(U_f, Um_f, U_o, Um_o, U_c, Um_c,
                                        b_f, b_o, b_c, mlx, hx, cfin, sent);
  histcast_kernel<<<16384, 128, 0, stream>>>(hx, (float*)d_out);
  finals_kernel<<<256, 256, 0, stream>>>(hx, cfin, (float*)d_out);
}